// Round 1
// 465.792 us; speedup vs baseline: 1.2453x; 1.2453x over previous
//
#include <hip/hip_runtime.h>

// ---------------------------------------------------------------------------
// LSTM cell, fully fused: gates = [x|h] @ [Wx|Wh]^T + (bx+bh), nonlinearity
// in the GEMM epilogue. W is cast to bf16 with gate-interleaved rows
// (n' = (s>>4)*64 + g*16 + (s&15)) so each lane's 4 N-fragments are the 4
// gates of the SAME (batch,s) element -> no cross-lane, no gates buffer.
//
// GEMM: 256x256 tile, BK=64, 512 thr (8 waves 2Mx4N), 8-phase schedule
// (T1 XCD swizzle + T2 LDS XOR swizzle + T3/T4 counted vmcnt + T5 setprio).
// ---------------------------------------------------------------------------

typedef __bf16 bf16;
typedef __attribute__((ext_vector_type(8))) __bf16 bf16x8;
typedef __attribute__((ext_vector_type(4))) float f32x4;

#define BATCH 4096
#define SIZE  2048
#define KCAT  4096          // concatenated K (x | h)
#define NTOT  8192          // 4 gates * SIZE output columns
#define BM 256
#define BN 256
#define BK 64
#define NT (KCAT / BK)      // 64 K-tiles

__device__ __forceinline__ bf16 f2bf(float f) {
    unsigned u = __builtin_bit_cast(unsigned, f);
    u += 0x7fffu + ((u >> 16) & 1u);          // round-to-nearest-even
    unsigned short h = (unsigned short)(u >> 16);
    return __builtin_bit_cast(bf16, h);
}

__device__ __forceinline__ void gld_lds16(const bf16* g, bf16* l) {
    __builtin_amdgcn_global_load_lds(
        (__attribute__((address_space(1))) void*)(const_cast<bf16*>(g)),
        (__attribute__((address_space(3))) void*)l,
        16, 0, 0);
}

// ---------------------------------------------------------------------------
// Cast fp32 -> bf16, K-concat [srcA|srcB], all addressing via shifts.
// MODE 0: dst row = src row (activations: x|h).
// MODE 1: dst row n' -> src row g*2048 + s with s=(n'>>6)*16+(n'&15),
//         g=(n'>>4)&3  (weights, gate-interleaved).
// ---------------------------------------------------------------------------
template <int MODE>
__global__ __launch_bounds__(256) void cast_concat(
    const float* __restrict__ srcA, const float* __restrict__ srcB,
    bf16* __restrict__ dst)
{
    long t = (long)blockIdx.x * 256 + threadIdx.x;   // one per 8 elements
    long e = t << 3;
    long nprime = e >> 12;                           // dst row (K=4096)
    int  col    = (int)(e & 4095);
    long srow;
    if (MODE == 0) {
        srow = nprime;
    } else {
        int t16 = (int)(nprime & 15);
        int g   = (int)((nprime >> 4) & 3);
        long s  = ((nprime >> 6) << 4) + t16;
        srow = (long)g * SIZE + s;
    }
    const float* src = (col < SIZE) ? (srcA + (srow << 11) + col)
                                    : (srcB + (srow << 11) + (col - SIZE));
    f32x4 v0 = *(const f32x4*)src;
    f32x4 v1 = *(const f32x4*)(src + 4);
    bf16x8 o;
    o[0] = f2bf(v0[0]); o[1] = f2bf(v0[1]); o[2] = f2bf(v0[2]); o[3] = f2bf(v0[3]);
    o[4] = f2bf(v1[0]); o[5] = f2bf(v1[1]); o[6] = f2bf(v1[2]); o[7] = f2bf(v1[3]);
    *(bf16x8*)(dst + e) = o;
}

// ---------------------------------------------------------------------------
__device__ __forceinline__ float sigm(float x) {
    return 1.f / (1.f + __expf(-x));
}
__device__ __forceinline__ float tanh_fast(float x) {
    float e = __expf(2.f * x);                   // inf-safe: 1 - 2/(e+1)
    return 1.f - 2.f / (e + 1.f);
}

#define MFMA16(ai, bj, cij) \
    cij = __builtin_amdgcn_mfma_f32_16x16x32_bf16(ai, bj, cij, 0, 0, 0)

// ---------------------------------------------------------------------------
// Fused GEMM + LSTM, 8-phase 256^2 template.
// LDS map (bf16 elems): A slot s half h at (s<<14)+(h<<13); B at +32768.
// Half-tile = [128 rows][64 cols], row = 128 B, XOR-swizzled:
//   byte_in_row ^= ((row & 7) << 4)   (involution, 16B-chunk preserving)
// Staging writes LINEAR LDS (global_load_lds requirement) from a
// pre-inverse-swizzled global source; ds_read applies the same XOR.
// ---------------------------------------------------------------------------
__global__ __launch_bounds__(512, 2) void gemm_lstm(
    const bf16* __restrict__ A, const bf16* __restrict__ W,
    const float* __restrict__ bxg, const float* __restrict__ bhg,
    const float* __restrict__ c, float* __restrict__ out)
{
    __shared__ __align__(16) bf16 sAB[65536];    // 128 KiB

    const int tid  = threadIdx.x;
    const int lane = tid & 63;
    const int wave = tid >> 6;
    const int wm   = wave >> 2;                  // 0..1 (M half)
    const int wn   = wave & 3;                   // 0..3 (N quarter)

    // T1: XCD-aware bijective swizzle, 512 wgs -> 8 chunks of 8x8 tiles
    const int orig = blockIdx.x;
    const int xcd  = orig & 7;
    const int loc  = orig >> 3;                  // 0..63
    const int bxt  = (xcd & 3) * 8 + (loc & 7);  // 0..31  (N tile)
    const int byt  = (xcd >> 2) * 8 + (loc >> 3);// 0..15  (M tile)
    const int m0 = byt * BM;
    const int n0 = bxt * BN;

    // ---- staging addressing (pre-inverse-swizzled global source) ----
    // chunk q (16B): LDS row q>>3, LDS 16B-slot q&7 -> logical slot
    // (q&7)^(row&7).  Thread does q=tid and q=tid+512 (row += 64).
    const int grow0 = tid >> 3;                          // 0..63
    const int colE  = (((tid & 7) ^ (grow0 & 7)) << 3);  // elems 0..56
    const bf16* pA = A + (size_t)(m0 + grow0) * KCAT + colE;
    const bf16* pB = W + (size_t)(n0 + grow0) * KCAT + colE;

#define STAGE_A(t, h) do {                                                   \
        const bf16* _g = pA + (size_t)(h) * (128 * KCAT) + (size_t)(t) * BK; \
        const int _l = (((t) & 1) << 14) + ((h) << 13) + tid * 8;            \
        gld_lds16(_g,                     &sAB[_l]);                         \
        gld_lds16(_g + (size_t)64 * KCAT, &sAB[_l + 4096]);                  \
    } while (0)
#define STAGE_B(t, h) do {                                                   \
        const bf16* _g = pB + (size_t)(h) * (128 * KCAT) + (size_t)(t) * BK; \
        const int _l = 32768 + (((t) & 1) << 14) + ((h) << 13) + tid * 8;    \
        gld_lds16(_g,                     &sAB[_l]);                         \
        gld_lds16(_g + (size_t)64 * KCAT, &sAB[_l + 4096]);                  \
    } while (0)

    // ---- fragment read addressing (swizzled ds_read_b128) ----
    // A-frag (16x16x32): row = mi*16 + (lane&15), col_byte = ks*64 +
    // (lane>>4)*16, swizzle-xor = ((row&7)<<4) = ((lane&7)<<4).
    const int l15   = lane & 15;
    const int swzX  = (lane & 7) << 4;                         // byte xor
    const int cSwz0 = (( (lane >> 4) << 4)        ^ swzX) >> 1; // elems, ks=0
    const int cSwz1 = ((64 | ((lane >> 4) << 4))  ^ swzX) >> 1; // elems, ks=1
    const int aR = l15 * 64;                       // + mi*1024
    const int bR = ((wn & 1) * 64 + l15) * 64;     // + nj*1024

    f32x4 acc[8][4];
#pragma unroll
    for (int i = 0; i < 8; i++)
#pragma unroll
        for (int j = 0; j < 4; j++)
            acc[i][j] = (f32x4){0.f, 0.f, 0.f, 0.f};

    // ---- prologue: T0 complete + T1's B halves (3 half-tiles ahead max) ----
    STAGE_A(0, 0); STAGE_A(0, 1); STAGE_B(0, 0); STAGE_B(0, 1);
    STAGE_B(1, 0); STAGE_B(1, 1);
    asm volatile("s_waitcnt vmcnt(4)" ::: "memory");   // T0's 8 loads landed
    __builtin_amdgcn_s_barrier();

    // ---- main loop: 4 phases per K-tile (8 per slot pair) ----
    // stage plan (steady state, tile t group):
    //   p1: A(t+1,h0)  p2: A(t+1,h1)   [slot t+1: prev reads done @ t-1 p3]
    //   p3: B(t+2,h0)  p4: B(t+2,h1)   [slot t:   B reads done @ t p2]
    // vmcnt(4) at p4 = exactly the p3+p4 stages issued after T_{t+1}'s last.
    for (int t = 0; t < NT; ++t) {
        const int aBase = ((t & 1) << 14) + (wm << 13);
        const int bBase = 32768 + ((t & 1) << 14) + ((wn >> 1) << 13);
        bf16x8 a[4][2], b[4][2];

        // ================= phase 1: quadrant (M0-3, N0-1) =================
#pragma unroll
        for (int i = 0; i < 4; ++i) {
            a[i][0] = *(const bf16x8*)&sAB[aBase + i * 1024 + aR + cSwz0];
            a[i][1] = *(const bf16x8*)&sAB[aBase + i * 1024 + aR + cSwz1];
        }
#pragma unroll
        for (int j = 0; j < 2; ++j) {
            b[j][0] = *(const bf16x8*)&sAB[bBase + j * 1024 + bR + cSwz0];
            b[j][1] = *(const bf16x8*)&sAB[bBase + j * 1024 + bR + cSwz1];
        }
        if (t + 1 < NT) STAGE_A(t + 1, 0);
        __builtin_amdgcn_s_barrier();
        __builtin_amdgcn_s_setprio(1);
#pragma unroll
        for (int i = 0; i < 4; ++i)
#pragma unroll
            for (int j = 0; j < 2; ++j) {
                MFMA16(a[i][0], b[j][0], acc[i][j]);
                MFMA16(a[i][1], b[j][1], acc[i][j]);
            }
        __builtin_amdgcn_s_setprio(0);
        __builtin_amdgcn_s_barrier();

        // ================= phase 2: quadrant (M0-3, N2-3) =================
#pragma unroll
        for (int j = 2; j < 4; ++j) {
            b[j][0] = *(const bf16x8*)&sAB[bBase + j * 1024 + bR + cSwz0];
            b[j][1] = *(const bf16x8*)&sAB[bBase + j * 1024 + bR + cSwz1];
        }
        if (t + 1 < NT) STAGE_A(t + 1, 1);
        __builtin_amdgcn_s_barrier();
        __builtin_amdgcn_s_setprio(1);
#pragma unroll
        for (int i = 0; i < 4; ++i)
#pragma unroll
            for (int j = 2; j < 4; ++j) {
                MFMA16(a[i][0], b[j][0], acc[i][j]);
                MFMA16(a[i][1], b[j][1], acc[i][j]);
            }
        __builtin_amdgcn_s_setprio(0);
        __builtin_amdgcn_s_barrier();

        // ================= phase 3: quadrant (M4-7, N2-3) =================
#pragma unroll
        for (int i = 0; i < 4; ++i) {            // overwrite a[] with M4-7
            a[i][0] = *(const bf16x8*)&sAB[aBase + (4 + i) * 1024 + aR + cSwz0];
            a[i][1] = *(const bf16x8*)&sAB[aBase + (4 + i) * 1024 + aR + cSwz1];
        }
        if (t + 2 < NT) STAGE_B(t + 2, 0);
        __builtin_amdgcn_s_barrier();
        __builtin_amdgcn_s_setprio(1);
#pragma unroll
        for (int i = 0; i < 4; ++i)
#pragma unroll
            for (int j = 2; j < 4; ++j) {
                MFMA16(a[i][0], b[j][0], acc[4 + i][j]);
                MFMA16(a[i][1], b[j][1], acc[4 + i][j]);
            }
        __builtin_amdgcn_s_setprio(0);
        __builtin_amdgcn_s_barrier();

        // ================= phase 4: quadrant (M4-7, N0-1) =================
        if (t + 2 < NT) STAGE_B(t + 2, 1);
        __builtin_amdgcn_s_barrier();
        __builtin_amdgcn_s_setprio(1);
#pragma unroll
        for (int i = 0; i < 4; ++i)
#pragma unroll
            for (int j = 0; j < 2; ++j) {
                MFMA16(a[i][0], b[j][0], acc[4 + i][j]);
                MFMA16(a[i][1], b[j][1], acc[4 + i][j]);
            }
        __builtin_amdgcn_s_setprio(0);
        if (t + 2 < NT) asm volatile("s_waitcnt vmcnt(4)" ::: "memory");
        else            asm volatile("s_waitcnt vmcnt(0)" ::: "memory");
        __builtin_amdgcn_s_barrier();
    }
#undef STAGE_A
#undef STAGE_B

    // ------------------------------------------------------------------
    // Epilogue. C/D layout: col=lane&15, row=(lane>>4)*4+reg.
    // n' = n0 + wn*64 + nj*16 + l15 -> gate = nj, s = (bxt*4+wn)*16 + l15.
    // ------------------------------------------------------------------
    const int s   = (bxt * 4 + wn) * 16 + l15;
    const float b_i = bxg[0 * SIZE + s] + bhg[0 * SIZE + s];
    const float b_f = bxg[1 * SIZE + s] + bhg[1 * SIZE + s];
    const float b_o = bxg[2 * SIZE + s] + bhg[2 * SIZE + s];
    const float b_c = bxg[3 * SIZE + s] + bhg[3 * SIZE + s];

    const int row0 = m0 + wm * 128 + (lane >> 4) * 4;
    float* hout = out;
    float* cout = out + (size_t)BATCH * SIZE;

#pragma unroll
    for (int mi = 0; mi < 8; ++mi) {
#pragma unroll
        for (int r = 0; r < 4; ++r) {
            const int row = row0 + mi * 16 + r;
            const size_t idx = (size_t)row * SIZE + s;
            float i_ = sigm(acc[mi][0][r] + b_i);
            float f_ = sigm(acc[mi][1][r] + b_f);
            float o_ = sigm(acc[mi][2][r] + b_o);
            float cc = tanh_fast(acc[mi][3][r] + b_c);
            float cn = f_ * c[idx] + i_ * cc;
            hout[idx] = o_ * tanh_fast(cn);
            cout[idx] = cn;
        }
    }
}

// ---------------------------------------------------------------------------
extern "C" void kernel_launch(void* const* d_in, const int* in_sizes, int n_in,
                              void* d_out, int out_size, void* d_ws, size_t ws_size,
                              hipStream_t stream) {
    const float* x  = (const float*)d_in[0];
    const float* h  = (const float*)d_in[1];
    const float* c  = (const float*)d_in[2];
    const float* Wx = (const float*)d_in[3];   // (4,2048,2048)
    const float* bx = (const float*)d_in[4];   // (4,2048)
    const float* Wh = (const float*)d_in[5];
    const float* bh = (const float*)d_in[6];
    float* out = (float*)d_out;

    char* w = (char*)d_ws;
    bf16* Acat = (bf16*)w;                           // 32 MiB
    bf16* Wcat = (bf16*)(w + (size_t)33554432);      // 64 MiB

    // 1) casts: A_cat = [x|h] (4096x4096); W_cat gate-interleaved (8192x4096)
    cast_concat<0><<<(BATCH * (size_t)KCAT / 8) / 256, 256, 0, stream>>>(
        x, h, Acat);
    cast_concat<1><<<(NTOT * (size_t)KCAT / 8) / 256, 256, 0, stream>>>(
        Wx, Wh, Wcat);

    // 2) fused gates GEMM (M=4096, N=8192, K=4096) + bias + LSTM nonlinearity
    gemm_lstm<<<dim3(512), 512, 0, stream>>>(Acat, Wcat, bx, bh, c, out);
}

// Round 2
// 465.038 us; speedup vs baseline: 1.2473x; 1.0016x over previous
//
#include <hip/hip_runtime.h>

// ---------------------------------------------------------------------------
// LSTM cell, fully fused: gates = [x|h] @ [Wx|Wh]^T + (bx+bh), nonlinearity
// in the GEMM epilogue. W is cast to bf16 with gate-interleaved rows
// (n' = (s>>4)*64 + g*16 + (s&15)) so each lane's 4 N-fragments are the 4
// gates of the SAME (batch,s) element -> no cross-lane, no gates buffer.
//
// GEMM: 256x256 tile, BK=64, 512 thr (8 waves 2Mx4N), 8-phase schedule
// (T1 XCD swizzle + T2 LDS XOR swizzle + T3/T4 counted vmcnt + T5 setprio).
// R2: k-outer MFMA ordering (acc dep distance 1 -> 8); casts merged into one
// launch, 16 elems/thread.
// ---------------------------------------------------------------------------

typedef __bf16 bf16;
typedef __attribute__((ext_vector_type(8))) __bf16 bf16x8;
typedef __attribute__((ext_vector_type(4))) float f32x4;

#define BATCH 4096
#define SIZE  2048
#define KCAT  4096          // concatenated K (x | h)
#define NTOT  8192          // 4 gates * SIZE output columns
#define BM 256
#define BN 256
#define BK 64
#define NT (KCAT / BK)      // 64 K-tiles

__device__ __forceinline__ bf16 f2bf(float f) {
    unsigned u = __builtin_bit_cast(unsigned, f);
    u += 0x7fffu + ((u >> 16) & 1u);          // round-to-nearest-even
    unsigned short h = (unsigned short)(u >> 16);
    return __builtin_bit_cast(bf16, h);
}

__device__ __forceinline__ void gld_lds16(const bf16* g, bf16* l) {
    __builtin_amdgcn_global_load_lds(
        (__attribute__((address_space(1))) void*)(const_cast<bf16*>(g)),
        (__attribute__((address_space(3))) void*)l,
        16, 0, 0);
}

// ---------------------------------------------------------------------------
// Cast fp32 -> bf16, K-concat [srcA|srcB]. 16 elems per thread.
// MODE 0: dst row = src row (activations: x|h).
// MODE 1: dst row n' -> src row g*2048 + s with s=(n'>>6)*16+(n'&15),
//         g=(n'>>4)&3  (weights, gate-interleaved).
// ---------------------------------------------------------------------------
template <int MODE>
__device__ __forceinline__ void cast16(
    const float* __restrict__ srcA, const float* __restrict__ srcB,
    bf16* __restrict__ dst, long t)
{
    long e = t << 4;                                 // 16 elems, no row straddle
    long nprime = e >> 12;                           // dst row (K=4096)
    int  col    = (int)(e & 4095);
    long srow;
    if (MODE == 0) {
        srow = nprime;
    } else {
        int t16 = (int)(nprime & 15);
        int g   = (int)((nprime >> 4) & 3);
        long s  = ((nprime >> 6) << 4) + t16;
        srow = (long)g * SIZE + s;
    }
    const float* src = (col < SIZE) ? (srcA + (srow << 11) + col)
                                    : (srcB + (srow << 11) + (col - SIZE));
    f32x4 v0 = *(const f32x4*)(src);
    f32x4 v1 = *(const f32x4*)(src + 4);
    f32x4 v2 = *(const f32x4*)(src + 8);
    f32x4 v3 = *(const f32x4*)(src + 12);
    bf16x8 o0, o1;
    o0[0] = f2bf(v0[0]); o0[1] = f2bf(v0[1]); o0[2] = f2bf(v0[2]); o0[3] = f2bf(v0[3]);
    o0[4] = f2bf(v1[0]); o0[5] = f2bf(v1[1]); o0[6] = f2bf(v1[2]); o0[7] = f2bf(v1[3]);
    o1[0] = f2bf(v2[0]); o1[1] = f2bf(v2[1]); o1[2] = f2bf(v2[2]); o1[3] = f2bf(v2[3]);
    o1[4] = f2bf(v3[0]); o1[5] = f2bf(v3[1]); o1[6] = f2bf(v3[2]); o1[7] = f2bf(v3[3]);
    *(bf16x8*)(dst + e)     = o0;
    *(bf16x8*)(dst + e + 8) = o1;
}

// blocks [0, 4096): Acat (4096x4096 elems). blocks [4096, 12288): Wcat.
__global__ __launch_bounds__(256) void cast_concat_all(
    const float* __restrict__ x,  const float* __restrict__ h,
    const float* __restrict__ Wx, const float* __restrict__ Wh,
    bf16* __restrict__ Acat, bf16* __restrict__ Wcat)
{
    int b = blockIdx.x;
    if (b < 4096) {
        long t = (long)b * 256 + threadIdx.x;
        cast16<0>(x, h, Acat, t);
    } else {
        long t = (long)(b - 4096) * 256 + threadIdx.x;
        cast16<1>(Wx, Wh, Wcat, t);
    }
}

// ---------------------------------------------------------------------------
__device__ __forceinline__ float sigm(float x) {
    return 1.f / (1.f + __expf(-x));
}
__device__ __forceinline__ float tanh_fast(float x) {
    float e = __expf(2.f * x);                   // inf-safe: 1 - 2/(e+1)
    return 1.f - 2.f / (e + 1.f);
}

#define MFMA16(ai, bj, cij) \
    cij = __builtin_amdgcn_mfma_f32_16x16x32_bf16(ai, bj, cij, 0, 0, 0)

// ---------------------------------------------------------------------------
// Fused GEMM + LSTM, 8-phase 256^2 template.
// LDS map (bf16 elems): A slot s half h at (s<<14)+(h<<13); B at +32768.
// Half-tile = [128 rows][64 cols], row = 128 B, XOR-swizzled:
//   byte_in_row ^= ((row & 7) << 4)   (involution, 16B-chunk preserving)
// Staging writes LINEAR LDS (global_load_lds requirement) from a
// pre-inverse-swizzled global source; ds_read applies the same XOR.
// ---------------------------------------------------------------------------
__global__ __launch_bounds__(512, 2) void gemm_lstm(
    const bf16* __restrict__ A, const bf16* __restrict__ W,
    const float* __restrict__ bxg, const float* __restrict__ bhg,
    const float* __restrict__ c, float* __restrict__ out)
{
    __shared__ __align__(16) bf16 sAB[65536];    // 128 KiB

    const int tid  = threadIdx.x;
    const int lane = tid & 63;
    const int wave = tid >> 6;
    const int wm   = wave >> 2;                  // 0..1 (M half)
    const int wn   = wave & 3;                   // 0..3 (N quarter)

    // T1: XCD-aware bijective swizzle, 512 wgs -> 8 chunks of 8x8 tiles
    const int orig = blockIdx.x;
    const int xcd  = orig & 7;
    const int loc  = orig >> 3;                  // 0..63
    const int bxt  = (xcd & 3) * 8 + (loc & 7);  // 0..31  (N tile)
    const int byt  = (xcd >> 2) * 8 + (loc >> 3);// 0..15  (M tile)
    const int m0 = byt * BM;
    const int n0 = bxt * BN;

    // ---- staging addressing (pre-inverse-swizzled global source) ----
    // chunk q (16B): LDS row q>>3, LDS 16B-slot q&7 -> logical slot
    // (q&7)^(row&7).  Thread does q=tid and q=tid+512 (row += 64).
    const int grow0 = tid >> 3;                          // 0..63
    const int colE  = (((tid & 7) ^ (grow0 & 7)) << 3);  // elems 0..56
    const bf16* pA = A + (size_t)(m0 + grow0) * KCAT + colE;
    const bf16* pB = W + (size_t)(n0 + grow0) * KCAT + colE;

#define STAGE_A(t, h) do {                                                   \
        const bf16* _g = pA + (size_t)(h) * (128 * KCAT) + (size_t)(t) * BK; \
        const int _l = (((t) & 1) << 14) + ((h) << 13) + tid * 8;            \
        gld_lds16(_g,                     &sAB[_l]);                         \
        gld_lds16(_g + (size_t)64 * KCAT, &sAB[_l + 4096]);                  \
    } while (0)
#define STAGE_B(t, h) do {                                                   \
        const bf16* _g = pB + (size_t)(h) * (128 * KCAT) + (size_t)(t) * BK; \
        const int _l = 32768 + (((t) & 1) << 14) + ((h) << 13) + tid * 8;    \
        gld_lds16(_g,                     &sAB[_l]);                         \
        gld_lds16(_g + (size_t)64 * KCAT, &sAB[_l + 4096]);                  \
    } while (0)

    // ---- fragment read addressing (swizzled ds_read_b128) ----
    // A-frag (16x16x32): row = mi*16 + (lane&15), col_byte = ks*64 +
    // (lane>>4)*16, swizzle-xor = ((row&7)<<4) = ((lane&7)<<4).
    const int l15   = lane & 15;
    const int swzX  = (lane & 7) << 4;                         // byte xor
    const int cSwz0 = (( (lane >> 4) << 4)        ^ swzX) >> 1; // elems, ks=0
    const int cSwz1 = ((64 | ((lane >> 4) << 4))  ^ swzX) >> 1; // elems, ks=1
    const int aR = l15 * 64;                       // + mi*1024
    const int bR = ((wn & 1) * 64 + l15) * 64;     // + nj*1024

    f32x4 acc[8][4];
#pragma unroll
    for (int i = 0; i < 8; i++)
#pragma unroll
        for (int j = 0; j < 4; j++)
            acc[i][j] = (f32x4){0.f, 0.f, 0.f, 0.f};

    // ---- prologue: T0 complete + T1's B halves (3 half-tiles ahead max) ----
    STAGE_A(0, 0); STAGE_A(0, 1); STAGE_B(0, 0); STAGE_B(0, 1);
    STAGE_B(1, 0); STAGE_B(1, 1);
    asm volatile("s_waitcnt vmcnt(4)" ::: "memory");   // T0's 8 loads landed
    __builtin_amdgcn_s_barrier();

    // ---- main loop: 4 phases per K-tile ----
    // stage plan (steady state, tile t group):
    //   p1: A(t+1,h0)  p2: A(t+1,h1)   [slot t+1: prev reads done @ t-1 p3]
    //   p3: B(t+2,h0)  p4: B(t+2,h1)   [slot t:   B reads done @ t p2]
    // vmcnt(4) at p4 drains A(t+1)+B(t+1), leaves B(t+2) in flight.
    for (int t = 0; t < NT; ++t) {
        const int aBase = ((t & 1) << 14) + (wm << 13);
        const int bBase = 32768 + ((t & 1) << 14) + ((wn >> 1) << 13);
        bf16x8 a[4][2], b[4][2];

        // ================= phase 1: quadrant (M0-3, N0-1) =================
#pragma unroll
        for (int i = 0; i < 4; ++i) {
            a[i][0] = *(const bf16x8*)&sAB[aBase + i * 1024 + aR + cSwz0];
            a[i][1] = *(const bf16x8*)&sAB[aBase + i * 1024 + aR + cSwz1];
        }
#pragma unroll
        for (int j = 0; j < 2; ++j) {
            b[j][0] = *(const bf16x8*)&sAB[bBase + j * 1024 + bR + cSwz0];
            b[j][1] = *(const bf16x8*)&sAB[bBase + j * 1024 + bR + cSwz1];
        }
        if (t + 1 < NT) STAGE_A(t + 1, 0);
        __builtin_amdgcn_s_barrier();
        __builtin_amdgcn_s_setprio(1);
#pragma unroll
        for (int k = 0; k < 2; ++k)                  // k-outer: acc dep dist 8
#pragma unroll
            for (int i = 0; i < 4; ++i)
#pragma unroll
                for (int j = 0; j < 2; ++j)
                    MFMA16(a[i][k], b[j][k], acc[i][j]);
        __builtin_amdgcn_s_setprio(0);
        __builtin_amdgcn_s_barrier();

        // ================= phase 2: quadrant (M0-3, N2-3) =================
#pragma unroll
        for (int j = 2; j < 4; ++j) {
            b[j][0] = *(const bf16x8*)&sAB[bBase + j * 1024 + bR + cSwz0];
            b[j][1] = *(const bf16x8*)&sAB[bBase + j * 1024 + bR + cSwz1];
        }
        if (t + 1 < NT) STAGE_A(t + 1, 1);
        __builtin_amdgcn_s_barrier();
        __builtin_amdgcn_s_setprio(1);
#pragma unroll
        for (int k = 0; k < 2; ++k)
#pragma unroll
            for (int i = 0; i < 4; ++i)
#pragma unroll
                for (int j = 2; j < 4; ++j)
                    MFMA16(a[i][k], b[j][k], acc[i][j]);
        __builtin_amdgcn_s_setprio(0);
        __builtin_amdgcn_s_barrier();

        // ================= phase 3: quadrant (M4-7, N2-3) =================
#pragma unroll
        for (int i = 0; i < 4; ++i) {            // overwrite a[] with M4-7
            a[i][0] = *(const bf16x8*)&sAB[aBase + (4 + i) * 1024 + aR + cSwz0];
            a[i][1] = *(const bf16x8*)&sAB[aBase + (4 + i) * 1024 + aR + cSwz1];
        }
        if (t + 2 < NT) STAGE_B(t + 2, 0);
        __builtin_amdgcn_s_barrier();
        __builtin_amdgcn_s_setprio(1);
#pragma unroll
        for (int k = 0; k < 2; ++k)
#pragma unroll
            for (int i = 0; i < 4; ++i)
#pragma unroll
                for (int j = 2; j < 4; ++j)
                    MFMA16(a[i][k], b[j][k], acc[4 + i][j]);
        __builtin_amdgcn_s_setprio(0);
        __builtin_amdgcn_s_barrier();

        // ================= phase 4: quadrant (M4-7, N0-1) =================
        if (t + 2 < NT) STAGE_B(t + 2, 1);
        __builtin_amdgcn_s_barrier();
        __builtin_amdgcn_s_setprio(1);
#pragma unroll
        for (int k = 0; k < 2; ++k)
#pragma unroll
            for (int i = 0; i < 4; ++i)
#pragma unroll
                for (int j = 0; j < 2; ++j)
                    MFMA16(a[i][k], b[j][k], acc[4 + i][j]);
        __builtin_amdgcn_s_setprio(0);
        if (t + 2 < NT) asm volatile("s_waitcnt vmcnt(4)" ::: "memory");
        else            asm volatile("s_waitcnt vmcnt(0)" ::: "memory");
        __builtin_amdgcn_s_barrier();
    }
#undef STAGE_A
#undef STAGE_B

    // ------------------------------------------------------------------
    // Epilogue. C/D layout: col=lane&15, row=(lane>>4)*4+reg.
    // n' = n0 + wn*64 + nj*16 + l15 -> gate = nj, s = (bxt*4+wn)*16 + l15.
    // ------------------------------------------------------------------
    const int s   = (bxt * 4 + wn) * 16 + l15;
    const float b_i = bxg[0 * SIZE + s] + bhg[0 * SIZE + s];
    const float b_f = bxg[1 * SIZE + s] + bhg[1 * SIZE + s];
    const float b_o = bxg[2 * SIZE + s] + bhg[2 * SIZE + s];
    const float b_c = bxg[3 * SIZE + s] + bhg[3 * SIZE + s];

    const int row0 = m0 + wm * 128 + (lane >> 4) * 4;
    float* hout = out;
    float* cout = out + (size_t)BATCH * SIZE;

#pragma unroll
    for (int mi = 0; mi < 8; ++mi) {
#pragma unroll
        for (int r = 0; r < 4; ++r) {
            const int row = row0 + mi * 16 + r;
            const size_t idx = (size_t)row * SIZE + s;
            float i_ = sigm(acc[mi][0][r] + b_i);
            float f_ = sigm(acc[mi][1][r] + b_f);
            float o_ = sigm(acc[mi][2][r] + b_o);
            float cc = tanh_fast(acc[mi][3][r] + b_c);
            float cn = f_ * c[idx] + i_ * cc;
            hout[idx] = o_ * tanh_fast(cn);
            cout[idx] = cn;
        }
    }
}

// ---------------------------------------------------------------------------
extern "C" void kernel_launch(void* const* d_in, const int* in_sizes, int n_in,
                              void* d_out, int out_size, void* d_ws, size_t ws_size,
                              hipStream_t stream) {
    const float* x  = (const float*)d_in[0];
    const float* h  = (const float*)d_in[1];
    const float* c  = (const float*)d_in[2];
    const float* Wx = (const float*)d_in[3];   // (4,2048,2048)
    const float* bx = (const float*)d_in[4];   // (4,2048)
    const float* Wh = (const float*)d_in[5];
    const float* bh = (const float*)d_in[6];
    float* out = (float*)d_out;

    char* w = (char*)d_ws;
    bf16* Acat = (bf16*)w;                           // 32 MiB
    bf16* Wcat = (bf16*)(w + (size_t)33554432);      // 64 MiB

    // 1) single cast launch: A_cat = [x|h]; W_cat gate-interleaved
    cast_concat_all<<<12288, 256, 0, stream>>>(x, h, Wx, Wh, Acat, Wcat);

    // 2) fused gates GEMM (M=4096, N=8192, K=4096) + bias + LSTM nonlinearity
    gemm_lstm<<<dim3(512), 512, 0, stream>>>(Acat, Wcat, bx, bh, c, out);
}